// Round 4
// baseline (768.597 us; speedup 1.0000x reference)
//
#include <hip/hip_runtime.h>
#include <hip/hip_bf16.h>
#include <stdint.h>

// ---------------------------------------------------------------------------
// BinaryMLP fused, round 4: latency-first.
// Round-3 post-mortem: ~5.2k cycles per K-step vs 78 cycles of MFMA — every
// step paid full memory latency because (a) prefetch depth was 1, and
// (b) __syncthreads() drains vmcnt(0), killing in-flight prefetches 25x in L1.
// Fixes: 4-deep register prefetch for W (all layers) and x (L1);
// raw `s_waitcnt lgkmcnt(0)` + `s_barrier` instead of __syncthreads (vmcnt is
// NEVER drained); L1 K padded to 896 so the pipeline is a clean multiple of 4.
// ---------------------------------------------------------------------------

typedef __attribute__((ext_vector_type(8))) short short8;   // 8 bf16
typedef __attribute__((ext_vector_type(4))) float f32x4;    // MFMA accum

#define THREADS 512
#define BM      64
#define HID     512
#define K1      784
#define K1P     896             // padded: 28 K-tiles of 32
#define BK      32
#define NK1     (K1P / BK)      // 28
#define NK2     (HID / BK)      // 16
#define WCHUNK  (HID * BK * 2)  // 32768 B : one K-tile of a 512-row weight panel

#define W1_OFF  0
#define W1_BYTES (NK1 * WCHUNK)             // 917504
#define W2_OFF  (W1_OFF + W1_BYTES)
#define W2_BYTES (NK2 * WCHUNK)             // 524288
#define W3_OFF  (W2_OFF + W2_BYTES)
#define W4_OFF  (W3_OFF + W2_BYTES)
#define W4_BYTES (16 * HID * 2)             // 16384 (rows 10..15 zero)
#define WS_BYTES (W4_OFF + W4_BYTES)        // 1982464

#define H_BYTES  (BM * HID * 2)             // 65536
#define XBUF0    H_BYTES
#define XBUF_SZ  (BM * BK * 2)              // 4096
#define LDS_TOTAL (H_BYTES + 2 * XBUF_SZ)   // 73728

#define LGKM0_BARRIER()  do {                                   \
    asm volatile("s_waitcnt lgkmcnt(0)" ::: "memory");          \
    __builtin_amdgcn_s_barrier();                               \
} while (0)

__device__ __forceinline__ unsigned short bfu(float f) {
    __hip_bfloat16 h = __float2bfloat16(f);
    return *reinterpret_cast<unsigned short*>(&h);
}

// ---------------------------------------------------------------------------
// prep: binarize/convert weights into ws, per-K-tile [n][kk] row-major chunks
// (exact MFMA B-fragment order, n-stride 64B). w1 zero-padded to K=896.
// ---------------------------------------------------------------------------
__global__ void prep_weights(const float* __restrict__ w1, const float* __restrict__ w2,
                             const float* __restrict__ w3, const float* __restrict__ w4,
                             unsigned char* __restrict__ ws)
{
    int id = blockIdx.x * blockDim.x + threadIdx.x;
    const int T1 = HID * (K1P / 16);    // 28672
    const int T2 = HID * (HID / 16);    // 16384
    const int T4 = 16 * (HID / 16);     // 512

    unsigned short v[16];

    if (id < T1) {
        int n = id / (K1P / 16), j = id % (K1P / 16);
        int kp0 = j * 16;
#pragma unroll
        for (int i = 0; i < 16; ++i) {
            int kp = kp0 + i;
            v[i] = (kp < K1) ? ((w1[n * K1 + kp] >= 0.0f) ? 0x3F80u : 0xBF80u) : 0;
        }
        unsigned off = W1_OFF + (kp0 >> 5) * WCHUNK + n * 64 + (kp0 & 31) * 2;
        *(short8*)(ws + off)      = *(short8*)&v[0];
        *(short8*)(ws + off + 16) = *(short8*)&v[8];
        return;
    }
    id -= T1;
    if (id < T2) {
        int n = id / (HID / 16), j = id % (HID / 16);
        int kp0 = j * 16;
#pragma unroll
        for (int i = 0; i < 16; ++i)
            v[i] = (w2[n * HID + kp0 + i] >= 0.0f) ? 0x3F80u : 0xBF80u;
        unsigned off = W2_OFF + (kp0 >> 5) * WCHUNK + n * 64 + (kp0 & 31) * 2;
        *(short8*)(ws + off)      = *(short8*)&v[0];
        *(short8*)(ws + off + 16) = *(short8*)&v[8];
        return;
    }
    id -= T2;
    if (id < T2) {
        int n = id / (HID / 16), j = id % (HID / 16);
        int kp0 = j * 16;
#pragma unroll
        for (int i = 0; i < 16; ++i)
            v[i] = (w3[n * HID + kp0 + i] >= 0.0f) ? 0x3F80u : 0xBF80u;
        unsigned off = W3_OFF + (kp0 >> 5) * WCHUNK + n * 64 + (kp0 & 31) * 2;
        *(short8*)(ws + off)      = *(short8*)&v[0];
        *(short8*)(ws + off + 16) = *(short8*)&v[8];
        return;
    }
    id -= T2;
    if (id < T4) {
        int n = id / (HID / 16), j = id % (HID / 16);
        int kp0 = j * 16;
#pragma unroll
        for (int i = 0; i < 16; ++i)
            v[i] = (n < 10) ? bfu(w4[n * HID + kp0 + i]) : 0;
        unsigned off = W4_OFF + n * 1024 + kp0 * 2;   // plain [16][512]
        *(short8*)(ws + off)      = *(short8*)&v[0];
        *(short8*)(ws + off + 16) = *(short8*)&v[8];
    }
}

// ---------------------------------------------------------------------------
// fused MLP: 1 block = 64 batch rows, 8 waves each owning 64x64 output
// ---------------------------------------------------------------------------
__global__ __launch_bounds__(THREADS, 4)
void fused_mlp(const float* __restrict__ x,
               const unsigned char* __restrict__ ws,
               const float* __restrict__ b1, const float* __restrict__ b2,
               const float* __restrict__ b3, const float* __restrict__ b4,
               float* __restrict__ out)
{
    extern __shared__ unsigned char lds[];
    const int tid  = threadIdx.x;
    const int lane = tid & 63;
    const int wave = tid >> 6;           // 0..7 : N-slice of 64 cols
    const int lr   = lane & 15;
    const int lg   = lane >> 4;
    const int row_base = blockIdx.x * BM;

    // H (swizzled) byte offset for (row, byte-col)
    auto h_off = [&](int row, int bc) -> unsigned {
        return ((unsigned)(row * 1024 + bc)) ^ (unsigned)((row & 7) << 4);
    };
    // xbuf (swizzled) byte offset
    auto x_off = [&](int buf, int row, int bc) -> unsigned {
        return XBUF0 + buf * XBUF_SZ
             + (((unsigned)(row * 64 + bc)) ^ (unsigned)((row & 7) << 4));
    };

    // W prefetch register sets, reused by all layers
    short8 p0[4], p1[4], p2[4], p3[4];

    // ---------------- Layer 1: x (4-deep pipelined via LDS dbuf) -> h1 -----
    f32x4 acc[4][4];
#pragma unroll
    for (int mf = 0; mf < 4; ++mf)
#pragma unroll
        for (int nf = 0; nf < 4; ++nf)
            acc[mf][nf] = (f32x4){0.f, 0.f, 0.f, 0.f};

    // epilogue: acc -> relu(acc+bias) -> bf16 -> H (swizzled)
    auto epilogueToH = [&](const float* __restrict__ bias) {
#pragma unroll
        for (int nf = 0; nf < 4; ++nf) {
            int col = wave * 64 + nf * 16 + lr;
            float bv = bias[col];
#pragma unroll
            for (int mf = 0; mf < 4; ++mf) {
#pragma unroll
                for (int r = 0; r < 4; ++r) {
                    int row = mf * 16 + lg * 4 + r;
                    float vv = acc[mf][nf][r] + bv;
                    vv = vv > 0.0f ? vv : 0.0f;
                    *(unsigned short*)(lds + h_off(row, col * 2)) = bfu(vv);
                }
            }
        }
    };

    {
        const unsigned char* wB1 = ws + W1_OFF + wave * 4096 + lr * 64 + lg * 16;
        const int srow = tid >> 3, sq = tid & 7;   // staging: 8 lanes/row
        const float* xrow = x + (size_t)(row_base + srow) * K1;

        auto xload = [&](int t) -> float4 {
            int col = t * BK + sq * 4;
            return (col < K1) ? *(const float4*)(xrow + col)
                              : make_float4(0.f, 0.f, 0.f, 0.f);
        };
        auto stage_write = [&](int buf, float4 v) {
            uint2 pk;
            pk.x = (unsigned)bfu(v.x) | ((unsigned)bfu(v.y) << 16);
            pk.y = (unsigned)bfu(v.z) | ((unsigned)bfu(v.w) << 16);
            *(uint2*)(lds + x_off(buf, srow, sq * 8)) = pk;
        };
        auto loadB1 = [&](short8 (&P)[4], int t) {
            if (t < NK1) {
                const unsigned char* bb = wB1 + (size_t)t * WCHUNK;
#pragma unroll
                for (int nf = 0; nf < 4; ++nf)
                    P[nf] = *(const short8*)(bb + nf * 1024);
            }
        };
        auto l1_compute = [&](int bufc, short8 (&P)[4]) {
            short8 a[4];
#pragma unroll
            for (int mf = 0; mf < 4; ++mf)
                a[mf] = *(const short8*)(lds + x_off(bufc, mf * 16 + lr, lg * 16));
#pragma unroll
            for (int mf = 0; mf < 4; ++mf)
#pragma unroll
                for (int nf = 0; nf < 4; ++nf)
                    acc[mf][nf] = __builtin_amdgcn_mfma_f32_16x16x32_bf16(a[mf], P[nf], acc[mf][nf], 0, 0, 0);
        };

        // prologue: tile0 -> LDS buf0; x tiles 1..4 and W tiles 0..3 in regs
        stage_write(0, xload(0));
        float4 xq1 = xload(1), xq2 = xload(2), xq3 = xload(3), xq0 = xload(4);
        loadB1(p0, 0); loadB1(p1, 1); loadB1(p2, 2); loadB1(p3, 3);
        LGKM0_BARRIER();

        // step s: compute buf[s&1] with p[s%4]; write x tile s+1 (loaded at
        // s-3) to buf[(s+1)&1]; issue x tile s+5 and W tile s+4. vmcnt never
        // drained: the barrier only waits lgkm (LDS visibility).
#define L1S(J, PB, XQ) {                                        \
        float4 xnew = xload(kt + (J) + 5);                      \
        l1_compute((J) & 1, PB);                                \
        loadB1(PB, kt + (J) + 4);                               \
        stage_write(((J) + 1) & 1, XQ);                         \
        XQ = xnew;                                              \
        LGKM0_BARRIER();                                        \
    }

#pragma unroll 1
        for (int kt = 0; kt < NK1; kt += 4) {
            L1S(0, p0, xq1)
            L1S(1, p1, xq2)
            L1S(2, p2, xq3)
            L1S(3, p3, xq0)
        }
#undef L1S

        epilogueToH(b1);           // H untouched until here
        LGKM0_BARRIER();           // h1 visible
    }

    // ---------------- Layers 2 & 3: A from H (read-only), B 4-deep ---------
#pragma unroll 1
    for (int layer = 0; layer < 2; ++layer) {
        const unsigned char* wb = ws + (layer == 0 ? W2_OFF : W3_OFF)
                                + wave * 4096 + lr * 64 + lg * 16;
        const float* bias = (layer == 0) ? b2 : b3;

#pragma unroll
        for (int mf = 0; mf < 4; ++mf)
#pragma unroll
            for (int nf = 0; nf < 4; ++nf)
                acc[mf][nf] = (f32x4){0.f, 0.f, 0.f, 0.f};

        auto loadB2 = [&](short8 (&P)[4], int t) {
            if (t < NK2) {
                const unsigned char* bb = wb + (size_t)t * WCHUNK;
#pragma unroll
                for (int nf = 0; nf < 4; ++nf)
                    P[nf] = *(const short8*)(bb + nf * 1024);
            }
        };
        auto l23_compute = [&](short8 (&P)[4], int ktc) {
            short8 a[4];
#pragma unroll
            for (int mf = 0; mf < 4; ++mf)
                a[mf] = *(const short8*)(lds + h_off(mf * 16 + lr, ktc * 64 + lg * 16));
#pragma unroll
            for (int mf = 0; mf < 4; ++mf)
#pragma unroll
                for (int nf = 0; nf < 4; ++nf)
                    acc[mf][nf] = __builtin_amdgcn_mfma_f32_16x16x32_bf16(a[mf], P[nf], acc[mf][nf], 0, 0, 0);
        };

        loadB2(p0, 0); loadB2(p1, 1); loadB2(p2, 2); loadB2(p3, 3);
#pragma unroll 1
        for (int kt = 0; kt < NK2; kt += 4) {
            l23_compute(p0, kt + 0); loadB2(p0, kt + 4);
            l23_compute(p1, kt + 1); loadB2(p1, kt + 5);
            l23_compute(p2, kt + 2); loadB2(p2, kt + 6);
            l23_compute(p3, kt + 3); loadB2(p3, kt + 7);
        }

        LGKM0_BARRIER();           // all waves' H reads done before overwrite
        epilogueToH(bias);
        LGKM0_BARRIER();           // new H visible
    }

    // ---------------- Layer 4: h3 @ w4^T (16-col padded, 10 real) ----------
    if (wave < 4) {
        const unsigned char* w4b = ws + W4_OFF + lr * 1024 + lg * 16;
        const int m = wave * 16 + lr;
        short8 w4f[16];
#pragma unroll
        for (int kt = 0; kt < NK2; ++kt)
            w4f[kt] = *(const short8*)(w4b + kt * 64);
        f32x4 acc4 = (f32x4){0.f, 0.f, 0.f, 0.f};
#pragma unroll
        for (int kt = 0; kt < NK2; ++kt) {
            short8 a = *(const short8*)(lds + h_off(m, kt * 64 + lg * 16));
            acc4 = __builtin_amdgcn_mfma_f32_16x16x32_bf16(a, w4f[kt], acc4, 0, 0, 0);
        }
        if (lr < 10) {
            float bv = b4[lr];
#pragma unroll
            for (int r = 0; r < 4; ++r) {
                int row = row_base + wave * 16 + lg * 4 + r;
                out[(size_t)row * 10 + lr] = acc4[r] + bv;
            }
        }
    }
}

extern "C" void kernel_launch(void* const* d_in, const int* in_sizes, int n_in,
                              void* d_out, int out_size, void* d_ws, size_t ws_size,
                              hipStream_t stream) {
    const float* x  = (const float*)d_in[0];
    const float* w1 = (const float*)d_in[1];
    const float* b1 = (const float*)d_in[2];
    const float* w2 = (const float*)d_in[3];
    const float* b2 = (const float*)d_in[4];
    const float* w3 = (const float*)d_in[5];
    const float* b3 = (const float*)d_in[6];
    const float* w4 = (const float*)d_in[7];
    const float* b4 = (const float*)d_in[8];
    float* out = (float*)d_out;
    unsigned char* ws = (unsigned char*)d_ws;

    if (ws_size < (size_t)WS_BYTES) return;

    const int B = in_sizes[0] / K1;           // 65536
    const int nblk = B / BM;                  // 1024

    (void)hipFuncSetAttribute((const void*)fused_mlp,
                              hipFuncAttributeMaxDynamicSharedMemorySize, LDS_TOTAL);

    const int prep_total = HID * (K1P / 16) + 2 * HID * (HID / 16) + 16 * (HID / 16);
    prep_weights<<<(prep_total + 255) / 256, 256, 0, stream>>>(w1, w2, w3, w4, ws);
    fused_mlp<<<nblk, THREADS, LDS_TOTAL, stream>>>(x, ws, b1, b2, b3, b4, out);
}

// Round 5
// 231.259 us; speedup vs baseline: 3.3235x; 3.3235x over previous
//
#include <hip/hip_runtime.h>
#include <hip/hip_bf16.h>
#include <stdint.h>

// ---------------------------------------------------------------------------
// BinaryMLP fused, round 5: round-4 spilled (depth-4 prefetch blew the
// 128-VGPR cap -> 1.7GB scratch). Same latency attack, sized to the budget:
//  - W register prefetch depth 2 (32 VGPR), all layers, vmcnt NEVER drained
//  - L1 x staged in groups of 2 K-tiles via 2x8KB LDS dbuf (13 barriers)
//  - lgkm-only barriers (s_waitcnt lgkmcnt(0); s_barrier)
//  - K1 padded to 832 (26 tiles, even ladder)
// Budget: acc 64 + W 32 + x 8 + temps ~= 125 VGPR, no spill.
// ---------------------------------------------------------------------------

typedef __attribute__((ext_vector_type(8))) short short8;   // 8 bf16
typedef __attribute__((ext_vector_type(4))) float f32x4;    // MFMA accum

#define THREADS 512
#define BM      64
#define HID     512
#define K1      784
#define K1P     832             // 26 K-tiles of 32
#define BK      32
#define NK1     (K1P / BK)      // 26
#define NK2     (HID / BK)      // 16
#define WCHUNK  (HID * BK * 2)  // 32768 B per K-tile of a 512-row weight panel

#define W1_OFF  0
#define W1_BYTES (NK1 * WCHUNK)             // 851968
#define W2_OFF  (W1_OFF + W1_BYTES)
#define W2_BYTES (NK2 * WCHUNK)             // 524288
#define W3_OFF  (W2_OFF + W2_BYTES)
#define W4_OFF  (W3_OFF + W2_BYTES)
#define W4_BYTES (16 * HID * 2)             // 16384 (rows 10..15 zero)
#define WS_BYTES (W4_OFF + W4_BYTES)        // 1916928

#define H_BYTES  (BM * HID * 2)             // 65536
#define XBUF0    H_BYTES
#define XTILE_SZ (BM * BK * 2)              // 4096 per K-tile
#define XGRP_SZ  (2 * XTILE_SZ)             // 8192 per 2-tile group
#define LDS_TOTAL (H_BYTES + 2 * XGRP_SZ)   // 81920 -> 2 blocks/CU

#define LGKM0_BARRIER()  do {                                   \
    asm volatile("s_waitcnt lgkmcnt(0)" ::: "memory");          \
    __builtin_amdgcn_s_barrier();                               \
} while (0)

__device__ __forceinline__ unsigned short bfu(float f) {
    __hip_bfloat16 h = __float2bfloat16(f);
    return *reinterpret_cast<unsigned short*>(&h);
}

// ---------------------------------------------------------------------------
// prep: binarize/convert weights into ws, per-K-tile [n][kk] row-major chunks
// (exact MFMA B-fragment order, n-stride 64B). w1 zero-padded to K=832.
// ---------------------------------------------------------------------------
__global__ void prep_weights(const float* __restrict__ w1, const float* __restrict__ w2,
                             const float* __restrict__ w3, const float* __restrict__ w4,
                             unsigned char* __restrict__ ws)
{
    int id = blockIdx.x * blockDim.x + threadIdx.x;
    const int T1 = HID * (K1P / 16);    // 26624
    const int T2 = HID * (HID / 16);    // 16384
    const int T4 = 16 * (HID / 16);     // 512

    unsigned short v[16];

    if (id < T1) {
        int n = id / (K1P / 16), j = id % (K1P / 16);
        int kp0 = j * 16;
#pragma unroll
        for (int i = 0; i < 16; ++i) {
            int kp = kp0 + i;
            v[i] = (kp < K1) ? ((w1[n * K1 + kp] >= 0.0f) ? 0x3F80u : 0xBF80u) : 0;
        }
        unsigned off = W1_OFF + (kp0 >> 5) * WCHUNK + n * 64 + (kp0 & 31) * 2;
        *(short8*)(ws + off)      = *(short8*)&v[0];
        *(short8*)(ws + off + 16) = *(short8*)&v[8];
        return;
    }
    id -= T1;
    if (id < T2) {
        int n = id / (HID / 16), j = id % (HID / 16);
        int kp0 = j * 16;
#pragma unroll
        for (int i = 0; i < 16; ++i)
            v[i] = (w2[n * HID + kp0 + i] >= 0.0f) ? 0x3F80u : 0xBF80u;
        unsigned off = W2_OFF + (kp0 >> 5) * WCHUNK + n * 64 + (kp0 & 31) * 2;
        *(short8*)(ws + off)      = *(short8*)&v[0];
        *(short8*)(ws + off + 16) = *(short8*)&v[8];
        return;
    }
    id -= T2;
    if (id < T2) {
        int n = id / (HID / 16), j = id % (HID / 16);
        int kp0 = j * 16;
#pragma unroll
        for (int i = 0; i < 16; ++i)
            v[i] = (w3[n * HID + kp0 + i] >= 0.0f) ? 0x3F80u : 0xBF80u;
        unsigned off = W3_OFF + (kp0 >> 5) * WCHUNK + n * 64 + (kp0 & 31) * 2;
        *(short8*)(ws + off)      = *(short8*)&v[0];
        *(short8*)(ws + off + 16) = *(short8*)&v[8];
        return;
    }
    id -= T2;
    if (id < T4) {
        int n = id / (HID / 16), j = id % (HID / 16);
        int kp0 = j * 16;
#pragma unroll
        for (int i = 0; i < 16; ++i)
            v[i] = (n < 10) ? bfu(w4[n * HID + kp0 + i]) : 0;
        unsigned off = W4_OFF + n * 1024 + kp0 * 2;   // plain [16][512]
        *(short8*)(ws + off)      = *(short8*)&v[0];
        *(short8*)(ws + off + 16) = *(short8*)&v[8];
    }
}

// ---------------------------------------------------------------------------
// fused MLP: 1 block = 64 batch rows, 8 waves each owning 64x64 output
// ---------------------------------------------------------------------------
__global__ __launch_bounds__(THREADS, 4)
void fused_mlp(const float* __restrict__ x,
               const unsigned char* __restrict__ ws,
               const float* __restrict__ b1, const float* __restrict__ b2,
               const float* __restrict__ b3, const float* __restrict__ b4,
               float* __restrict__ out)
{
    extern __shared__ unsigned char lds[];
    const int tid  = threadIdx.x;
    const int lane = tid & 63;
    const int wave = tid >> 6;           // 0..7 : N-slice of 64 cols
    const int lr   = lane & 15;
    const int lg   = lane >> 4;
    const int row_base = blockIdx.x * BM;

    // H (swizzled) byte offset
    auto h_off = [&](int row, int bc) -> unsigned {
        return ((unsigned)(row * 1024 + bc)) ^ (unsigned)((row & 7) << 4);
    };
    // x group buffer (swizzled) byte offset
    auto x_off = [&](int half, int t, int row, int bc) -> unsigned {
        return XBUF0 + half * XGRP_SZ + t * XTILE_SZ
             + (((unsigned)(row * 64 + bc)) ^ (unsigned)((row & 7) << 4));
    };

    f32x4 acc[4][4];
    auto zeroAcc = [&]() {
#pragma unroll
        for (int mf = 0; mf < 4; ++mf)
#pragma unroll
            for (int nf = 0; nf < 4; ++nf)
                acc[mf][nf] = (f32x4){0.f, 0.f, 0.f, 0.f};
    };

    // epilogue: acc -> relu(acc+bias) -> bf16 -> H (swizzled)
    auto epilogueToH = [&](const float* __restrict__ bias) {
#pragma unroll
        for (int nf = 0; nf < 4; ++nf) {
            int col = wave * 64 + nf * 16 + lr;
            float bv = bias[col];
#pragma unroll
            for (int mf = 0; mf < 4; ++mf) {
#pragma unroll
                for (int r = 0; r < 4; ++r) {
                    int row = mf * 16 + lg * 4 + r;
                    float vv = acc[mf][nf][r] + bv;
                    vv = vv > 0.0f ? vv : 0.0f;
                    *(unsigned short*)(lds + h_off(row, col * 2)) = bfu(vv);
                }
            }
        }
    };

    short8 p0[4], p1[4];   // depth-2 W prefetch, reused by all layers

    // ---------------- Layer 1: x (2-tile-group LDS dbuf) -> h1 -------------
    {
        zeroAcc();
        const unsigned char* wB1 = ws + W1_OFF + wave * 4096 + lr * 64 + lg * 16;
        const int srow = tid >> 3, sq = tid & 7;   // staging: 8 lanes/row
        const float* xrow = x + (size_t)(row_base + srow) * K1;

        auto xload = [&](int t) -> float4 {
            int col = t * BK + sq * 4;
            return (col < K1) ? *(const float4*)(xrow + col)
                              : make_float4(0.f, 0.f, 0.f, 0.f);
        };
        auto stage_write = [&](int half, int t, float4 v) {
            uint2 pk;
            pk.x = (unsigned)bfu(v.x) | ((unsigned)bfu(v.y) << 16);
            pk.y = (unsigned)bfu(v.z) | ((unsigned)bfu(v.w) << 16);
            *(uint2*)(lds + x_off(half, t, srow, sq * 8)) = pk;
        };
        auto loadB1 = [&](short8 (&P)[4], int t) {
            if (t < NK1) {
                const unsigned char* bb = wB1 + (size_t)t * WCHUNK;
#pragma unroll
                for (int nf = 0; nf < 4; ++nf)
                    P[nf] = *(const short8*)(bb + nf * 1024);
            }
        };
        auto l1_compute = [&](int half, int t, short8 (&P)[4]) {
            short8 a[4];
#pragma unroll
            for (int mf = 0; mf < 4; ++mf)
                a[mf] = *(const short8*)(lds + x_off(half, t, mf * 16 + lr, lg * 16));
#pragma unroll
            for (int mf = 0; mf < 4; ++mf)
#pragma unroll
                for (int nf = 0; nf < 4; ++nf)
                    acc[mf][nf] = __builtin_amdgcn_mfma_f32_16x16x32_bf16(a[mf], P[nf], acc[mf][nf], 0, 0, 0);
        };

        // prologue: group0 -> half0; group1 in regs; W tiles 0,1 in regs
        stage_write(0, 0, xload(0));
        stage_write(0, 1, xload(1));
        float4 xc0 = xload(2), xc1 = xload(3);     // group 1
        loadB1(p0, 0); loadB1(p1, 1);
        LGKM0_BARRIER();

        // 13 groups of 2 K-tiles
#pragma unroll 1
        for (int g = 0; g < 13; ++g) {
            float4 xn0, xn1;
            if (g < 11) { xn0 = xload(2 * g + 4); xn1 = xload(2 * g + 5); }
            else        { xn0 = xc0; xn1 = xc1; }       // dead values
            l1_compute(g & 1, 0, p0); loadB1(p0, 2 * g + 2);
            l1_compute(g & 1, 1, p1); loadB1(p1, 2 * g + 3);
            if (g < 12) {
                stage_write((g + 1) & 1, 0, xc0);
                stage_write((g + 1) & 1, 1, xc1);
            }
            xc0 = xn0; xc1 = xn1;
            LGKM0_BARRIER();
        }

        epilogueToH(b1);           // H untouched until here
        LGKM0_BARRIER();           // h1 visible
    }

    // ---------------- Layers 2 & 3: A from H (read-only), B depth-2 --------
#pragma unroll 1
    for (int layer = 0; layer < 2; ++layer) {
        const unsigned char* wb = ws + (layer == 0 ? W2_OFF : W3_OFF)
                                + wave * 4096 + lr * 64 + lg * 16;
        const float* bias = (layer == 0) ? b2 : b3;

        zeroAcc();

        auto loadB2 = [&](short8 (&P)[4], int t) {
            if (t < NK2) {
                const unsigned char* bb = wb + (size_t)t * WCHUNK;
#pragma unroll
                for (int nf = 0; nf < 4; ++nf)
                    P[nf] = *(const short8*)(bb + nf * 1024);
            }
        };
        auto l23_compute = [&](short8 (&P)[4], int ktc) {
            short8 a[4];
#pragma unroll
            for (int mf = 0; mf < 4; ++mf)
                a[mf] = *(const short8*)(lds + h_off(mf * 16 + lr, ktc * 64 + lg * 16));
#pragma unroll
            for (int mf = 0; mf < 4; ++mf)
#pragma unroll
                for (int nf = 0; nf < 4; ++nf)
                    acc[mf][nf] = __builtin_amdgcn_mfma_f32_16x16x32_bf16(a[mf], P[nf], acc[mf][nf], 0, 0, 0);
        };

        loadB2(p0, 0); loadB2(p1, 1);
#pragma unroll 1
        for (int kt = 0; kt < NK2; kt += 2) {
            l23_compute(p0, kt);     loadB2(p0, kt + 2);
            l23_compute(p1, kt + 1); loadB2(p1, kt + 3);
        }

        LGKM0_BARRIER();           // all waves' H reads done before overwrite
        epilogueToH(bias);
        LGKM0_BARRIER();           // new H visible
    }

    // ---------------- Layer 4: h3 @ w4^T (16-col padded, 10 real) ----------
    if (wave < 4) {
        const unsigned char* w4b = ws + W4_OFF + lr * 1024 + lg * 16;
        const int m = wave * 16 + lr;
        short8 w4f[16];
#pragma unroll
        for (int kt = 0; kt < NK2; ++kt)
            w4f[kt] = *(const short8*)(w4b + kt * 64);
        f32x4 acc4 = (f32x4){0.f, 0.f, 0.f, 0.f};
#pragma unroll
        for (int kt = 0; kt < NK2; ++kt) {
            short8 a = *(const short8*)(lds + h_off(m, kt * 64 + lg * 16));
            acc4 = __builtin_amdgcn_mfma_f32_16x16x32_bf16(a, w4f[kt], acc4, 0, 0, 0);
        }
        if (lr < 10) {
            float bv = b4[lr];
#pragma unroll
            for (int r = 0; r < 4; ++r) {
                int row = row_base + wave * 16 + lg * 4 + r;
                out[(size_t)row * 10 + lr] = acc4[r] + bv;
            }
        }
    }
}

extern "C" void kernel_launch(void* const* d_in, const int* in_sizes, int n_in,
                              void* d_out, int out_size, void* d_ws, size_t ws_size,
                              hipStream_t stream) {
    const float* x  = (const float*)d_in[0];
    const float* w1 = (const float*)d_in[1];
    const float* b1 = (const float*)d_in[2];
    const float* w2 = (const float*)d_in[3];
    const float* b2 = (const float*)d_in[4];
    const float* w3 = (const float*)d_in[5];
    const float* b3 = (const float*)d_in[6];
    const float* w4 = (const float*)d_in[7];
    const float* b4 = (const float*)d_in[8];
    float* out = (float*)d_out;
    unsigned char* ws = (unsigned char*)d_ws;

    if (ws_size < (size_t)WS_BYTES) return;

    const int B = in_sizes[0] / K1;           // 65536
    const int nblk = B / BM;                  // 1024

    (void)hipFuncSetAttribute((const void*)fused_mlp,
                              hipFuncAttributeMaxDynamicSharedMemorySize, LDS_TOTAL);

    const int prep_total = HID * (K1P / 16) + 2 * HID * (HID / 16) + 16 * (HID / 16);
    prep_weights<<<(prep_total + 255) / 256, 256, 0, stream>>>(w1, w2, w3, w4, ws);
    fused_mlp<<<nblk, THREADS, LDS_TOTAL, stream>>>(x, ws, b1, b2, b3, b4, out);
}

// Round 6
// 201.335 us; speedup vs baseline: 3.8175x; 1.1486x over previous
//
#include <hip/hip_runtime.h>
#include <hip/hip_bf16.h>
#include <stdint.h>

// ---------------------------------------------------------------------------
// BinaryMLP fused, round 6: bit-packed binary weights.
// R3/R5 post-mortem: per-K-step stalls (~220 cyc) from B-operand L2 latency;
// deeper VGPR prefetch spills (R4). Fix the FORMAT: binarized weights are
// 1 bit. Prep packs each wave's B-fragments as 1 dword/lane/K-tile; the
// K-loop loads 4 B/lane (depth-4 prefetch = 4 VGPR) and expands to bf16 +-1
// in registers (~64 VALU/kt on the underused VALU pipe, co-issues with MFMA).
// A-side from LDS (H tile, XOR-swizzled, addresses hoisted). w4 stays bf16.
// ---------------------------------------------------------------------------

typedef __attribute__((ext_vector_type(8))) short short8;   // 8 bf16
typedef __attribute__((ext_vector_type(4))) float f32x4;    // MFMA accum

#define THREADS 512
#define BM      64
#define HID     512
#define K1      784
#define K1P     832             // 26 K-tiles of 32
#define BK      32
#define NK1     (K1P / BK)      // 26
#define NK2     (HID / BK)      // 16

// mask layout per layer: [wave][kt][lane] dwords (256 B per wave-kt)
#define M1_OFF  0
#define M1_BYTES (8 * NK1 * 256)            // 53248
#define M2_OFF  (M1_OFF + M1_BYTES)
#define M2_BYTES (8 * NK2 * 256)            // 32768
#define M3_OFF  (M2_OFF + M2_BYTES)
#define W4_OFF  (M3_OFF + M2_BYTES)         // 118784
#define W4_BYTES (16 * HID * 2)             // 16384 (rows 10..15 zero)
#define WS_BYTES (W4_OFF + W4_BYTES)        // 135168

#define H_BYTES  (BM * HID * 2)             // 65536
#define XBUF0    H_BYTES
#define XTILE_SZ (BM * BK * 2)              // 4096 per K-tile
#define XGRP_SZ  (2 * XTILE_SZ)             // 8192 per 2-tile group
#define LDS_TOTAL (H_BYTES + 2 * XGRP_SZ)   // 81920 -> 2 blocks/CU

#define LGKM0_BARRIER()  do {                                   \
    asm volatile("s_waitcnt lgkmcnt(0)" ::: "memory");          \
    __builtin_amdgcn_s_barrier();                               \
} while (0)

__device__ __forceinline__ unsigned short bfu(float f) {
    __hip_bfloat16 h = __float2bfloat16(f);
    return *reinterpret_cast<unsigned short*>(&h);
}

// expand 8 sign bits (bits nf*8..nf*8+7 of m; 1 = negative) to 8 bf16 +-1
__device__ __forceinline__ short8 expand_frag(unsigned m, int nf) {
    const unsigned KP = 0x3F803F80u;        // {+1.0bf16, +1.0bf16}
    unsigned mm = m >> (nf * 8);
    union { short8 s8; unsigned u[4]; } r;
    r.u[0] = KP | ((mm & 1u) << 15)        | ((mm & 2u) << 30);
    r.u[1] = KP | (((mm >> 2) & 1u) << 15) | (((mm >> 2) & 2u) << 30);
    r.u[2] = KP | (((mm >> 4) & 1u) << 15) | (((mm >> 4) & 2u) << 30);
    r.u[3] = KP | (((mm >> 6) & 1u) << 15) | (((mm >> 6) & 2u) << 30);
    return r.s8;
}

// ---------------------------------------------------------------------------
// prep: pack sign bits in per-(wave,kt,lane) fragment order; w4 -> bf16 panel
// ---------------------------------------------------------------------------
__global__ void prep_weights(const float* __restrict__ w1, const float* __restrict__ w2,
                             const float* __restrict__ w3, const float* __restrict__ w4,
                             unsigned char* __restrict__ ws)
{
    int id = blockIdx.x * blockDim.x + threadIdx.x;
    const int T1 = 8 * NK1 * 64;        // 13312
    const int T2 = 8 * NK2 * 64;        // 8192
    const int T4 = 16 * (HID / 16);     // 512

    if (id < T1) {
        int wn = id / (NK1 * 64), rem = id % (NK1 * 64);
        int kt = rem / 64, lane = rem % 64;
        int lr = lane & 15, lg = lane >> 4;
        unsigned m = 0;
#pragma unroll
        for (int nf = 0; nf < 4; ++nf) {
            int n = wn * 64 + nf * 16 + lr;
#pragma unroll
            for (int j = 0; j < 8; ++j) {
                int k = kt * BK + lg * 8 + j;
                if (k < K1 && w1[n * K1 + k] < 0.0f) m |= 1u << (nf * 8 + j);
            }
        }
        *(unsigned*)(ws + M1_OFF + (size_t)id * 4) = m;
        return;
    }
    id -= T1;
    if (id < 2 * T2) {
        const float* w = (id < T2) ? w2 : w3;
        unsigned base = (id < T2) ? M2_OFF : M3_OFF;
        int iid = (id < T2) ? id : id - T2;
        int wn = iid / (NK2 * 64), rem = iid % (NK2 * 64);
        int kt = rem / 64, lane = rem % 64;
        int lr = lane & 15, lg = lane >> 4;
        unsigned m = 0;
#pragma unroll
        for (int nf = 0; nf < 4; ++nf) {
            int n = wn * 64 + nf * 16 + lr;
#pragma unroll
            for (int j = 0; j < 8; ++j) {
                int k = kt * BK + lg * 8 + j;
                if (w[n * HID + k] < 0.0f) m |= 1u << (nf * 8 + j);
            }
        }
        *(unsigned*)(ws + base + (size_t)iid * 4) = m;
        return;
    }
    id -= 2 * T2;
    if (id < T4) {
        int n = id / (HID / 16), j = id % (HID / 16);
        int kp0 = j * 16;
        unsigned short v[16];
#pragma unroll
        for (int i = 0; i < 16; ++i)
            v[i] = (n < 10) ? bfu(w4[n * HID + kp0 + i]) : 0;
        unsigned off = W4_OFF + n * 1024 + kp0 * 2;   // plain [16][512]
        *(short8*)(ws + off)      = *(short8*)&v[0];
        *(short8*)(ws + off + 16) = *(short8*)&v[8];
    }
}

// ---------------------------------------------------------------------------
// fused MLP: 1 block = 64 batch rows, 8 waves each owning 64x64 output
// ---------------------------------------------------------------------------
__global__ __launch_bounds__(THREADS, 4)
void fused_mlp(const float* __restrict__ x,
               const unsigned char* __restrict__ ws,
               const float* __restrict__ b1, const float* __restrict__ b2,
               const float* __restrict__ b3, const float* __restrict__ b4,
               float* __restrict__ out)
{
    extern __shared__ unsigned char lds[];
    const int tid  = threadIdx.x;
    const int lane = tid & 63;
    const int wave = tid >> 6;           // 0..7 : N-slice of 64 cols
    const int lr   = lane & 15;
    const int lg   = lane >> 4;
    const int row_base = blockIdx.x * BM;

    // hoisted swizzled base offsets (XOR bits 4..6; lr&7 is row&7 for rows mf*16+lr)
    const unsigned swz = (unsigned)((lr & 7) << 4);

    f32x4 acc[4][4];
    auto zeroAcc = [&]() {
#pragma unroll
        for (int mf = 0; mf < 4; ++mf)
#pragma unroll
            for (int nf = 0; nf < 4; ++nf)
                acc[mf][nf] = (f32x4){0.f, 0.f, 0.f, 0.f};
    };

    // epilogue: acc -> relu(acc+bias) -> bf16 -> H (swizzled)
    auto h_off = [&](int row, int bc) -> unsigned {
        return ((unsigned)(row * 1024 + bc)) ^ (unsigned)((row & 7) << 4);
    };
    auto epilogueToH = [&](const float* __restrict__ bias) {
#pragma unroll
        for (int nf = 0; nf < 4; ++nf) {
            int col = wave * 64 + nf * 16 + lr;
            float bv = bias[col];
#pragma unroll
            for (int mf = 0; mf < 4; ++mf) {
#pragma unroll
                for (int r = 0; r < 4; ++r) {
                    int row = mf * 16 + lg * 4 + r;
                    float vv = acc[mf][nf][r] + bv;
                    vv = vv > 0.0f ? vv : 0.0f;
                    *(unsigned short*)(lds + h_off(row, col * 2)) = bfu(vv);
                }
            }
        }
    };

    // ---------------- Layer 1: x (2-tile-group LDS dbuf) -> h1 -------------
    {
        zeroAcc();
        const unsigned char* mb1 = ws + M1_OFF + wave * (NK1 * 256) + lane * 4;
        const int srow = tid >> 3, sq = tid & 7;   // staging: 8 lanes/row
        const float* xrow = x + (size_t)(row_base + srow) * K1;

        auto xload = [&](int t) -> float4 {
            int col = t * BK + sq * 4;
            return (col < K1) ? *(const float4*)(xrow + col)
                              : make_float4(0.f, 0.f, 0.f, 0.f);
        };
        auto stage_write = [&](int half, int t, float4 v) {
            uint2 pk;
            pk.x = (unsigned)bfu(v.x) | ((unsigned)bfu(v.y) << 16);
            pk.y = (unsigned)bfu(v.z) | ((unsigned)bfu(v.w) << 16);
            unsigned off = XBUF0 + half * XGRP_SZ + t * XTILE_SZ
                         + (((unsigned)(srow * 64 + sq * 8)) ^ (unsigned)((srow & 7) << 4));
            *(uint2*)(lds + off) = pk;
        };
        auto mload1 = [&](int t) -> unsigned {
            int tc = t < NK1 ? t : NK1 - 1;
            return *(const unsigned*)(mb1 + tc * 256);
        };
        auto l1_compute = [&](int half, int t, unsigned m) {
            unsigned xb = (((unsigned)(lr * 64 + lg * 16)) ^ swz)
                        + XBUF0 + half * XGRP_SZ + t * XTILE_SZ;
            short8 a[4];
#pragma unroll
            for (int mf = 0; mf < 4; ++mf)
                a[mf] = *(const short8*)(lds + xb + mf * 1024);
#pragma unroll
            for (int nf = 0; nf < 4; ++nf) {
                short8 bf = expand_frag(m, nf);
#pragma unroll
                for (int mf = 0; mf < 4; ++mf)
                    acc[mf][nf] = __builtin_amdgcn_mfma_f32_16x16x32_bf16(a[mf], bf, acc[mf][nf], 0, 0, 0);
            }
        };

        // prologue: group0 -> half0; group1 x in regs; masks for kt 0,1
        stage_write(0, 0, xload(0));
        stage_write(0, 1, xload(1));
        float4 xc0 = xload(2), xc1 = xload(3);
        unsigned mg0 = mload1(0), mg1 = mload1(1);
        LGKM0_BARRIER();

#pragma unroll 1
        for (int g = 0; g < 13; ++g) {
            float4 xn0, xn1;
            if (g < 11) { xn0 = xload(2 * g + 4); xn1 = xload(2 * g + 5); }
            else        { xn0 = xc0; xn1 = xc1; }
            unsigned n0 = mload1(2 * g + 2), n1 = mload1(2 * g + 3);
            l1_compute(g & 1, 0, mg0);
            l1_compute(g & 1, 1, mg1);
            if (g < 12) {
                stage_write((g + 1) & 1, 0, xc0);
                stage_write((g + 1) & 1, 1, xc1);
            }
            xc0 = xn0; xc1 = xn1; mg0 = n0; mg1 = n1;
            LGKM0_BARRIER();
        }

        epilogueToH(b1);           // H untouched until here
        LGKM0_BARRIER();           // h1 visible
    }

    // ---------------- Layers 2 & 3: A from H (read-only), B = bitmasks -----
#pragma unroll 1
    for (int layer = 0; layer < 2; ++layer) {
        const unsigned char* mb = ws + (layer == 0 ? M2_OFF : M3_OFF)
                                + wave * (NK2 * 256) + lane * 4;
        const float* bias = (layer == 0) ? b2 : b3;

        zeroAcc();

        auto mload2 = [&](int t) -> unsigned {
            int tc = t < NK2 ? t : NK2 - 1;
            return *(const unsigned*)(mb + tc * 256);
        };
        auto l23_compute = [&](int kt, unsigned m) {
            unsigned ab = (((unsigned)(lr * 1024 + kt * 64 + lg * 16)) ^ swz);
            short8 a[4];
#pragma unroll
            for (int mf = 0; mf < 4; ++mf)
                a[mf] = *(const short8*)(lds + ab + mf * 16384);
#pragma unroll
            for (int nf = 0; nf < 4; ++nf) {
                short8 bf = expand_frag(m, nf);
#pragma unroll
                for (int mf = 0; mf < 4; ++mf)
                    acc[mf][nf] = __builtin_amdgcn_mfma_f32_16x16x32_bf16(a[mf], bf, acc[mf][nf], 0, 0, 0);
            }
        };

        unsigned q0 = mload2(0), q1 = mload2(1), q2 = mload2(2), q3 = mload2(3);
#pragma unroll 1
        for (int kt = 0; kt < NK2; kt += 4) {
            l23_compute(kt + 0, q0); q0 = mload2(kt + 4);
            l23_compute(kt + 1, q1); q1 = mload2(kt + 5);
            l23_compute(kt + 2, q2); q2 = mload2(kt + 6);
            l23_compute(kt + 3, q3); q3 = mload2(kt + 7);
        }

        LGKM0_BARRIER();           // all waves' H reads done before overwrite
        epilogueToH(bias);
        LGKM0_BARRIER();           // new H visible
    }

    // ---------------- Layer 4: h3 @ w4^T (16-col padded, 10 real) ----------
    if (wave < 4) {
        const unsigned char* w4b = ws + W4_OFF + lr * 1024 + lg * 16;
        const int m = wave * 16 + lr;
        short8 w4f[16];
#pragma unroll
        for (int kt = 0; kt < NK2; ++kt)
            w4f[kt] = *(const short8*)(w4b + kt * 64);
        f32x4 acc4 = (f32x4){0.f, 0.f, 0.f, 0.f};
#pragma unroll
        for (int kt = 0; kt < NK2; ++kt) {
            short8 a = *(const short8*)(lds + h_off(m, kt * 64 + lg * 16));
            acc4 = __builtin_amdgcn_mfma_f32_16x16x32_bf16(a, w4f[kt], acc4, 0, 0, 0);
        }
        if (lr < 10) {
            float bv = b4[lr];
#pragma unroll
            for (int r = 0; r < 4; ++r) {
                int row = row_base + wave * 16 + lg * 4 + r;
                out[(size_t)row * 10 + lr] = acc4[r] + bv;
            }
        }
    }
}

extern "C" void kernel_launch(void* const* d_in, const int* in_sizes, int n_in,
                              void* d_out, int out_size, void* d_ws, size_t ws_size,
                              hipStream_t stream) {
    const float* x  = (const float*)d_in[0];
    const float* w1 = (const float*)d_in[1];
    const float* b1 = (const float*)d_in[2];
    const float* w2 = (const float*)d_in[3];
    const float* b2 = (const float*)d_in[4];
    const float* w3 = (const float*)d_in[5];
    const float* b3 = (const float*)d_in[6];
    const float* w4 = (const float*)d_in[7];
    const float* b4 = (const float*)d_in[8];
    float* out = (float*)d_out;
    unsigned char* ws = (unsigned char*)d_ws;

    if (ws_size < (size_t)WS_BYTES) return;

    const int B = in_sizes[0] / K1;           // 65536
    const int nblk = B / BM;                  // 1024

    (void)hipFuncSetAttribute((const void*)fused_mlp,
                              hipFuncAttributeMaxDynamicSharedMemorySize, LDS_TOTAL);

    const int prep_total = 8 * NK1 * 64 + 2 * (8 * NK2 * 64) + 16 * (HID / 16);
    prep_weights<<<(prep_total + 255) / 256, 256, 0, stream>>>(w1, w2, w3, w4, ws);
    fused_mlp<<<nblk, THREADS, LDS_TOTAL, stream>>>(x, ws, b1, b2, b3, b4, out);
}

// Round 8
// 106.752 us; speedup vs baseline: 7.1998x; 1.8860x over previous
//
#include <hip/hip_runtime.h>
#include <hip/hip_bf16.h>
#include <stdint.h>

// ---------------------------------------------------------------------------
// BinaryMLP fused, round 8: round 7 (VALU diet) with the swizzle-carry bug
// fixed. R7 hoisted `hbase = (base ^ swz)` and added kt*64 OUTSIDE the XOR;
// kt*64 overlaps swizzle bit 6, so (a^s)+kt*64 != (a+kt*64)^s for lanes with
// lr&4 on odd kt (carry into bit 7) -> layers 2/3 read wrong H bytes.
// Rule: keep every offset that overlaps the XOR field INSIDE the XOR.
//  - LUT expansion: 16-entry LDS LUT (nibble -> 4 bf16 +-1)
//  - Operand swap: weights = MFMA A operand; epilogue via v_cvt_pk_bf16_f32
//  - L1 per-kt LDS dbuf, lgkm-only barriers; vmcnt never drained
//  - setprio(1/0) around MFMA clusters
// ---------------------------------------------------------------------------

typedef __attribute__((ext_vector_type(8))) short short8;   // 8 bf16
typedef __attribute__((ext_vector_type(4))) float f32x4;    // MFMA accum

#define THREADS 512
#define BM      64
#define HID     512
#define K1      784
#define K1P     832             // 26 K-tiles of 32
#define BK      32
#define NK1     (K1P / BK)      // 26
#define NK2     (HID / BK)      // 16

// mask layout per layer: [wave][kt][lane] dwords (256 B per wave-kt)
#define M1_OFF  0
#define M1_BYTES (8 * NK1 * 256)            // 53248
#define M2_OFF  (M1_OFF + M1_BYTES)
#define M2_BYTES (8 * NK2 * 256)            // 32768
#define M3_OFF  (M2_OFF + M2_BYTES)
#define W4_OFF  (M3_OFF + M2_BYTES)         // 118784
#define W4_BYTES (16 * HID * 2)             // 16384 (rows 10..15 zero)
#define WS_BYTES (W4_OFF + W4_BYTES)        // 135168

#define H_BYTES  (BM * HID * 2)             // 65536
#define XBUF0    H_BYTES
#define XTILE_SZ (BM * BK * 2)              // 4096 per K-tile
#define LUT_OFF  (XBUF0 + 2 * XTILE_SZ)     // 73728 (128-aligned)
#define LDS_TOTAL (LUT_OFF + 128)           // 73856 -> 2 blocks/CU

#define LGKM0_BARRIER()  do {                                   \
    asm volatile("s_waitcnt lgkmcnt(0)" ::: "memory");          \
    __builtin_amdgcn_s_barrier();                               \
} while (0)

__device__ __forceinline__ unsigned short bfu(float f) {
    __hip_bfloat16 h = __float2bfloat16(f);
    return *reinterpret_cast<unsigned short*>(&h);
}

__device__ __forceinline__ unsigned cvtpk(float lo, float hi) {
    unsigned d;
    asm("v_cvt_pk_bf16_f32 %0, %1, %2" : "=v"(d) : "v"(lo), "v"(hi));
    return d;
}

// ---------------------------------------------------------------------------
// prep: pack sign bits in per-(wave,kt,lane) fragment order (bit nf*8+j:
// n = wave*64+nf*16+(lane&15), k = kt*32+(lane>>4)*8+j); w4 -> bf16 panel.
// ---------------------------------------------------------------------------
__global__ void prep_weights(const float* __restrict__ w1, const float* __restrict__ w2,
                             const float* __restrict__ w3, const float* __restrict__ w4,
                             unsigned char* __restrict__ ws)
{
    int id = blockIdx.x * blockDim.x + threadIdx.x;
    const int T1 = 8 * NK1 * 64;        // 13312
    const int T2 = 8 * NK2 * 64;        // 8192
    const int T4 = 16 * (HID / 16);     // 512

    if (id < T1) {
        int wn = id / (NK1 * 64), rem = id % (NK1 * 64);
        int kt = rem / 64, lane = rem % 64;
        int lr = lane & 15, lg = lane >> 4;
        unsigned m = 0;
#pragma unroll
        for (int nf = 0; nf < 4; ++nf) {
            int n = wn * 64 + nf * 16 + lr;
#pragma unroll
            for (int j = 0; j < 8; ++j) {
                int k = kt * BK + lg * 8 + j;
                if (k < K1 && w1[n * K1 + k] < 0.0f) m |= 1u << (nf * 8 + j);
            }
        }
        *(unsigned*)(ws + M1_OFF + (size_t)id * 4) = m;
        return;
    }
    id -= T1;
    if (id < 2 * T2) {
        const float* w = (id < T2) ? w2 : w3;
        unsigned base = (id < T2) ? M2_OFF : M3_OFF;
        int iid = (id < T2) ? id : id - T2;
        int wn = iid / (NK2 * 64), rem = iid % (NK2 * 64);
        int kt = rem / 64, lane = rem % 64;
        int lr = lane & 15, lg = lane >> 4;
        unsigned m = 0;
#pragma unroll
        for (int nf = 0; nf < 4; ++nf) {
            int n = wn * 64 + nf * 16 + lr;
#pragma unroll
            for (int j = 0; j < 8; ++j) {
                int k = kt * BK + lg * 8 + j;
                if (w[n * HID + k] < 0.0f) m |= 1u << (nf * 8 + j);
            }
        }
        *(unsigned*)(ws + base + (size_t)iid * 4) = m;
        return;
    }
    id -= 2 * T2;
    if (id < T4) {
        int n = id / (HID / 16), j = id % (HID / 16);
        int kp0 = j * 16;
        unsigned short v[16];
#pragma unroll
        for (int i = 0; i < 16; ++i)
            v[i] = (n < 10) ? bfu(w4[n * HID + kp0 + i]) : 0;
        unsigned off = W4_OFF + n * 1024 + kp0 * 2;   // plain [16][512]
        *(short8*)(ws + off)      = *(short8*)&v[0];
        *(short8*)(ws + off + 16) = *(short8*)&v[8];
    }
}

// ---------------------------------------------------------------------------
// fused MLP: 1 block = 64 batch rows, 8 waves each owning 64 output cols
// ---------------------------------------------------------------------------
__global__ __launch_bounds__(THREADS, 4)
void fused_mlp(const float* __restrict__ x,
               const unsigned char* __restrict__ ws,
               const float* __restrict__ b1, const float* __restrict__ b2,
               const float* __restrict__ b3, const float* __restrict__ b4,
               float* __restrict__ out)
{
    extern __shared__ unsigned char lds[];
    const int tid  = threadIdx.x;
    const int lane = tid & 63;
    const int wave = tid >> 6;           // 0..7 : N-slice of 64 cols
    const int lr   = lane & 15;
    const int lg   = lane >> 4;
    const int row_base = blockIdx.x * BM;
    const unsigned swz = (unsigned)((lr & 7) << 4);

    // sign LUT: nibble -> 4 bf16 (+1 / -1), 8 B per entry
    if (tid < 16) {
        unsigned e0 = ((tid & 1) ? 0xBF80u : 0x3F80u)
                    | (((tid & 2) ? 0xBF80u : 0x3F80u) << 16);
        unsigned e1 = ((tid & 4) ? 0xBF80u : 0x3F80u)
                    | (((tid & 8) ? 0xBF80u : 0x3F80u) << 16);
        uint2 e; e.x = e0; e.y = e1;
        *(uint2*)(lds + LUT_OFF + tid * 8) = e;
    }

    // acc[nf][mg]: MFMA tile = (weight cols nf*16, batch rows mg*16).
    // D layout (swapped operands): lane col = batch row (lane&15), lane row
    // quad = 4 consecutive n at n0 = wave*64 + nf*16 + lg*4.
    f32x4 acc[4][4];
    auto zeroAcc = [&]() {
#pragma unroll
        for (int nf = 0; nf < 4; ++nf)
#pragma unroll
            for (int mg = 0; mg < 4; ++mg)
                acc[nf][mg] = (f32x4){0.f, 0.f, 0.f, 0.f};
    };

    auto h_off = [&](int row, int bc) -> unsigned {
        return ((unsigned)(row * 1024 + bc)) ^ (unsigned)((row & 7) << 4);
    };

    // epilogue: relu(acc+bias) -> bf16 pairs (cvt_pk) -> ds_write_b64
    auto epilogueToH = [&](const float* __restrict__ bias) {
#pragma unroll
        for (int nf = 0; nf < 4; ++nf) {
            const int n0 = wave * 64 + nf * 16 + lg * 4;
            float4 bv = *(const float4*)(bias + n0);
#pragma unroll
            for (int mg = 0; mg < 4; ++mg) {
                float v0 = acc[nf][mg][0] + bv.x; v0 = v0 > 0.f ? v0 : 0.f;
                float v1 = acc[nf][mg][1] + bv.y; v1 = v1 > 0.f ? v1 : 0.f;
                float v2 = acc[nf][mg][2] + bv.z; v2 = v2 > 0.f ? v2 : 0.f;
                float v3 = acc[nf][mg][3] + bv.w; v3 = v3 > 0.f ? v3 : 0.f;
                uint2 d; d.x = cvtpk(v0, v1); d.y = cvtpk(v2, v3);
                int row = mg * 16 + lr;
                unsigned off = ((unsigned)(row * 1024 + n0 * 2)) ^ (unsigned)((row & 7) << 4);
                *(uint2*)(lds + off) = d;
            }
        }
    };

    // expand one 8-bit fragment via LUT (2 nibble lookups) -> short8
    auto lutA = [&](unsigned m, int nf) -> short8 {
        unsigned lo = (m >> (nf * 8)) & 15u;
        unsigned hi = (m >> (nf * 8 + 4)) & 15u;
        union { short8 s; uint2 d[2]; } r;
        r.d[0] = *(const uint2*)(lds + LUT_OFF + lo * 8);
        r.d[1] = *(const uint2*)(lds + LUT_OFF + hi * 8);
        return r.s;
    };

    // ---------------- Layer 1: x (per-kt LDS dbuf) -> h1 -------------------
    {
        zeroAcc();
        const unsigned char* mb1 = ws + M1_OFF + wave * (NK1 * 256) + lane * 4;
        const int srow = tid >> 3, sq = tid & 7;   // staging: 8 lanes/row
        const float* xrow = x + (size_t)(row_base + srow) * K1;
        const unsigned s_off = (((unsigned)(srow * 64 + sq * 8)) ^ (unsigned)((srow & 7) << 4)) + XBUF0;
        // safe hoist: XOR'd term < 1024; +buf*4096 / +mf*1024 are carry-free
        const unsigned xbase = (((unsigned)(lr * 64 + lg * 16)) ^ swz) + XBUF0;

        auto xload = [&](int t) -> float4 {
            int col = t * BK + sq * 4;
            return (col < K1) ? *(const float4*)(xrow + col)
                              : make_float4(0.f, 0.f, 0.f, 0.f);
        };
        auto stage_write = [&](int buf, float4 v) {
            uint2 pk; pk.x = cvtpk(v.x, v.y); pk.y = cvtpk(v.z, v.w);
            *(uint2*)(lds + s_off + buf * XTILE_SZ) = pk;
        };
        auto mload1 = [&](int t) -> unsigned {
            int tc = t < NK1 ? t : NK1 - 1;
            return *(const unsigned*)(mb1 + tc * 256);
        };
        auto l1_compute = [&](int buf, unsigned m) {
            unsigned xb = xbase + buf * XTILE_SZ;
            short8 B0 = *(const short8*)(lds + xb);
            short8 B1 = *(const short8*)(lds + xb + 1024);
            short8 B2 = *(const short8*)(lds + xb + 2048);
            short8 B3 = *(const short8*)(lds + xb + 3072);
            __builtin_amdgcn_s_setprio(1);
#pragma unroll
            for (int nf = 0; nf < 4; ++nf) {
                short8 A = lutA(m, nf);
                acc[nf][0] = __builtin_amdgcn_mfma_f32_16x16x32_bf16(A, B0, acc[nf][0], 0, 0, 0);
                acc[nf][1] = __builtin_amdgcn_mfma_f32_16x16x32_bf16(A, B1, acc[nf][1], 0, 0, 0);
                acc[nf][2] = __builtin_amdgcn_mfma_f32_16x16x32_bf16(A, B2, acc[nf][2], 0, 0, 0);
                acc[nf][3] = __builtin_amdgcn_mfma_f32_16x16x32_bf16(A, B3, acc[nf][3], 0, 0, 0);
            }
            __builtin_amdgcn_s_setprio(0);
        };

        // prologue: tile0 staged; tiles 1,2 in regs; masks 0,1 in regs
        stage_write(0, xload(0));
        float4 xc = xload(1), xn = xload(2);
        unsigned mc = mload1(0), mn = mload1(1);
        LGKM0_BARRIER();        // also publishes the LUT

#pragma unroll 1
        for (int kt = 0; kt < NK1; ++kt) {
            float4 xnew = xload(kt + 3);
            unsigned mnew = mload1(kt + 2);
            l1_compute(kt & 1, mc);
            stage_write((kt + 1) & 1, xc);
            xc = xn; xn = xnew; mc = mn; mn = mnew;
            LGKM0_BARRIER();
        }

        epilogueToH(b1);           // H untouched until here
        LGKM0_BARRIER();           // h1 visible
    }

    // ---------------- Layers 2 & 3: barrier-free, masks depth-4 ------------
#pragma unroll 1
    for (int layer = 0; layer < 2; ++layer) {
        const unsigned char* mb = ws + (layer == 0 ? M2_OFF : M3_OFF)
                                + wave * (NK2 * 256) + lane * 4;
        const float* bias = (layer == 0) ? b2 : b3;

        zeroAcc();

        auto mload2 = [&](int t) -> unsigned {
            int tc = t < NK2 ? t : NK2 - 1;
            return *(const unsigned*)(mb + tc * 256);
        };
        auto l23_compute = [&](int kt, unsigned m) {
            // BUGFIX (R7): kt*64 overlaps swizzle bit 6 -> must be INSIDE the XOR
            unsigned hb = (((unsigned)(lr * 1024 + kt * 64 + lg * 16)) ^ swz);
            short8 B0 = *(const short8*)(lds + hb);
            short8 B1 = *(const short8*)(lds + hb + 16384);
            short8 B2 = *(const short8*)(lds + hb + 32768);
            short8 B3 = *(const short8*)(lds + hb + 49152);
            __builtin_amdgcn_s_setprio(1);
#pragma unroll
            for (int nf = 0; nf < 4; ++nf) {
                short8 A = lutA(m, nf);
                acc[nf][0] = __builtin_amdgcn_mfma_f32_16x16x32_bf16(A, B0, acc[nf][0], 0, 0, 0);
                acc[nf][1] = __builtin_amdgcn_mfma_f32_16x16x32_bf16(A, B1, acc[nf][1], 0, 0, 0);
                acc[nf][2] = __builtin_amdgcn_mfma_f32_16x16x32_bf16(A, B2, acc[nf][2], 0, 0, 0);
                acc[nf][3] = __builtin_amdgcn_mfma_f32_16x16x32_bf16(A, B3, acc[nf][3], 0, 0, 0);
            }
            __builtin_amdgcn_s_setprio(0);
        };

        unsigned q0 = mload2(0), q1 = mload2(1), q2 = mload2(2), q3 = mload2(3);
#pragma unroll 1
        for (int kt = 0; kt < NK2; kt += 4) {
            l23_compute(kt + 0, q0); q0 = mload2(kt + 4);
            l23_compute(kt + 1, q1); q1 = mload2(kt + 5);
            l23_compute(kt + 2, q2); q2 = mload2(kt + 6);
            l23_compute(kt + 3, q3); q3 = mload2(kt + 7);
        }

        LGKM0_BARRIER();           // all waves' H reads done before overwrite
        epilogueToH(bias);
        LGKM0_BARRIER();           // new H visible
    }

    // ---------------- Layer 4: h3 @ w4^T (16-col padded, 10 real) ----------
    if (wave < 4) {
        const unsigned char* w4b = ws + W4_OFF + lr * 1024 + lg * 16;
        const int m = wave * 16 + lr;
        short8 w4f[16];
#pragma unroll
        for (int kt = 0; kt < NK2; ++kt)
            w4f[kt] = *(const short8*)(w4b + kt * 64);
        f32x4 acc4 = (f32x4){0.f, 0.f, 0.f, 0.f};
#pragma unroll
        for (int kt = 0; kt < NK2; ++kt) {
            short8 a = *(const short8*)(lds + h_off(m, kt * 64 + lg * 16));
            acc4 = __builtin_amdgcn_mfma_f32_16x16x32_bf16(a, w4f[kt], acc4, 0, 0, 0);
        }
        if (lr < 10) {
            float bv = b4[lr];
#pragma unroll
            for (int r = 0; r < 4; ++r) {
                int row = row_base + wave * 16 + lg * 4 + r;
                out[(size_t)row * 10 + lr] = acc4[r] + bv;
            }
        }
    }
}

extern "C" void kernel_launch(void* const* d_in, const int* in_sizes, int n_in,
                              void* d_out, int out_size, void* d_ws, size_t ws_size,
                              hipStream_t stream) {
    const float* x  = (const float*)d_in[0];
    const float* w1 = (const float*)d_in[1];
    const float* b1 = (const float*)d_in[2];
    const float* w2 = (const float*)d_in[3];
    const float* b2 = (const float*)d_in[4];
    const float* w3 = (const float*)d_in[5];
    const float* b3 = (const float*)d_in[6];
    const float* w4 = (const float*)d_in[7];
    const float* b4 = (const float*)d_in[8];
    float* out = (float*)d_out;
    unsigned char* ws = (unsigned char*)d_ws;

    if (ws_size < (size_t)WS_BYTES) return;

    const int B = in_sizes[0] / K1;           // 65536
    const int nblk = B / BM;                  // 1024

    (void)hipFuncSetAttribute((const void*)fused_mlp,
                              hipFuncAttributeMaxDynamicSharedMemorySize, LDS_TOTAL);

    const int prep_total = 8 * NK1 * 64 + 2 * (8 * NK2 * 64) + 16 * (HID / 16);
    prep_weights<<<(prep_total + 255) / 256, 256, 0, stream>>>(w1, w2, w3, w4, ws);
    fused_mlp<<<nblk, THREADS, LDS_TOTAL, stream>>>(x, ws, b1, b2, b3, b4, out);
}